// Round 11
// baseline (175.124 us; speedup 1.0000x reference)
//
#include <hip/hip_runtime.h>

#define NN 50000
#define NE 1600000
#define D 128
#define RPB 40        // rows per block in the GEMM epilogue (50000/40 = 1250 blocks)
#define NW 25000      // packed histogram words = NN/2 (100 KB LDS)
#define NCS 32        // src chunks (CHUNK_S = 50000)
#define CHUNK_S 50000
#define NCD 32        // dst chunks (CHUNK_D = 50000)
#define CHUNK_D 50000
#define NBS 196       // reduce_scan blocks = ceil(NN/256)

// ---- workspace layout (bytes), total 16,679,936 (< proven 19.88 MB budget) ----
#define WS_INV  0         // float NN
#define WS_CNT  204800    // int NN   (dst degree)
#define WS_OFF  409600    // int NN   (CSR offsets)
#define WS_BSUM 610304    // int NBS
#define WS_WT   614400    // float 128*128
#define WS_A    679936    // psrc_p u32 NCS*NW = 3.2 MB; later csr u16 NE = 3.2 MB
#define WS_B    3879936   // pdst_p u32 NCD*NW = 3.2 MB          } xnb (12.8 MB)
#define WS_C    7079936   // bases  int NCD*NN = 6.4 MB          } overlays B+C+D
#define WS_D    13479936  // xnb tail 3.2 MB                     } after fill
// xnb = [WS_B, WS_B + 12.8 MB) ; end = 16,679,936

// ---------------- fused: 1-pass src hist (32) + 1-pass dst hist (32) + W transpose (16) ----------------
// full-node-range histogram: 50000 bins packed 2-per-u32 in 100 KB LDS.
// per-(node,chunk) counts ~ Poisson(1) << 65536, so packed halves cannot carry.
__global__ __launch_bounds__(1024) void fused_pre(const int* __restrict__ ei,
                                                  const float* __restrict__ W,
                                                  unsigned* __restrict__ psrc_p,
                                                  unsigned* __restrict__ pdst_p,
                                                  float* __restrict__ Wt) {
    __shared__ unsigned h[NW];
    int bid = blockIdx.x;
    if (bid < NCS) {
        for (int j = threadIdx.x; j < NW; j += 1024) h[j] = 0;
        __syncthreads();
        const int* s = ei + bid * CHUNK_S;
        for (int i = threadIdx.x; i < CHUNK_S; i += 1024) {
            int v = s[i];
            atomicAdd(&h[v >> 1], 1u << ((v & 1) << 4));
        }
        __syncthreads();
        unsigned* p = psrc_p + (size_t)bid * NW;
        for (int j = threadIdx.x; j < NW; j += 1024) p[j] = h[j];
    } else if (bid < NCS + NCD) {
        int c = bid - NCS;
        for (int j = threadIdx.x; j < NW; j += 1024) h[j] = 0;
        __syncthreads();
        const int* d = ei + NE + c * CHUNK_D;
        for (int i = threadIdx.x; i < CHUNK_D; i += 1024) {
            int v = d[i];
            atomicAdd(&h[v >> 1], 1u << ((v & 1) << 4));
        }
        __syncthreads();
        unsigned* p = pdst_p + (size_t)c * NW;
        for (int j = threadIdx.x; j < NW; j += 1024) p[j] = h[j];
    } else {
        int i = (bid - NCS - NCD) * 1024 + threadIdx.x;  // 16 blocks x 1024 = 16384
        int c = i >> 7, k = i & 127;
        Wt[k * D + c] = W[i];
    }
}

// ---------------- inv/cnt from packed hists + per-block exclusive scan of cnt ----------------
__global__ __launch_bounds__(256) void reduce_scan(const unsigned* __restrict__ psrc_p,
                                                   const unsigned* __restrict__ pdst_p,
                                                   float* __restrict__ inv,
                                                   int* __restrict__ cnt,
                                                   int* __restrict__ off,
                                                   int* __restrict__ bsum) {
    __shared__ int sh[256];
    int tid = threadIdx.x;
    int k = blockIdx.x * 256 + tid;
    int t = 0;
    if (k < NN) {
        int j = k >> 1, shf = (k & 1) << 4;
        int s = 0;
#pragma unroll 8
        for (int c = 0; c < NCS; ++c) s += (psrc_p[(size_t)c * NW + j] >> shf) & 0xffffu;
#pragma unroll 8
        for (int c = 0; c < NCD; ++c) t += (pdst_p[(size_t)c * NW + j] >> shf) & 0xffffu;
        inv[k] = rsqrtf((float)s + 1.0f);
        cnt[k] = t;
    }
    sh[tid] = t;
    __syncthreads();
    for (int d = 1; d < 256; d <<= 1) {
        int v = (tid >= d) ? sh[tid - d] : 0;
        __syncthreads();
        sh[tid] += v;
        __syncthreads();
    }
    if (k < NN) off[k] = sh[tid] - t;  // exclusive within block
    if (tid == 255) bsum[blockIdx.x] = sh[255];
}

// ---------------- finalize off; expand packed counts -> absolute int bases [chunk][node] ----------------
__global__ __launch_bounds__(256) void scan_chunks(const unsigned* __restrict__ pdst_p,
                                                   int* __restrict__ bases,
                                                   int* __restrict__ off,
                                                   const int* __restrict__ bsum) {
    __shared__ int sb[256];
    int tid = threadIdx.x;
    int bi = blockIdx.x;
    sb[tid] = (tid < bi) ? bsum[tid] : 0;  // bi <= 195 < NBS
    __syncthreads();
    for (int d = 1; d < 256; d <<= 1) {
        int v = (tid >= d) ? sb[tid - d] : 0;
        __syncthreads();
        sb[tid] += v;
        __syncthreads();
    }
    int top = sb[255];
    int k = bi * 256 + tid;
    if (k >= NN) return;
    int run = off[k] + top;
    off[k] = run;  // final CSR offset
    int j = k >> 1, shf = (k & 1) << 4;
#pragma unroll 8
    for (int c = 0; c < NCD; ++c) {
        int v = (pdst_p[(size_t)c * NW + j] >> shf) & 0xffffu;
        bases[(size_t)c * NN + k] = run;
        run += v;
    }
}

// ---------------- place edges: 2 ranges x 32 chunks; int LDS cursors (100 KB) ----------------
__global__ __launch_bounds__(1024) void fill_sorted(const int* __restrict__ ei,
                                                    const int* __restrict__ bases,
                                                    unsigned short* __restrict__ csr) {
    __shared__ int cur[NW];  // 25000 nodes per range
    int R = blockIdx.x >> 5, c = blockIdx.x & 31;
    int lo = R * NW;
    const int* bslice = bases + (size_t)c * NN + lo;
    for (int j = threadIdx.x; j < NW; j += 1024) cur[j] = bslice[j];
    __syncthreads();
    const int* s = ei + c * CHUNK_D;
    const int* d = ei + NE + c * CHUNK_D;
    for (int i = threadIdx.x; i < CHUNK_D; i += 1024) {
        int kd = d[i] - lo;
        if ((unsigned)kd < NW) {
            int pos = atomicAdd(&cur[kd], 1);
            csr[pos] = (unsigned short)s[i];
        }
    }
}

// ---------------- xnb[n][c] = bf16_rne(x[n][c] * inv[n]), packed 2/u32 ----------------
__device__ __forceinline__ unsigned bf16_rne(float f) {
    unsigned u = __float_as_uint(f);
    return (u + 0x7fffu + ((u >> 16) & 1u)) >> 16;
}
__global__ void scale_kernel(const float* __restrict__ x, const float* __restrict__ inv,
                             unsigned* __restrict__ xnb4) {
    int i = blockIdx.x * blockDim.x + threadIdx.x;  // 0 .. NN*16-1
    if (i >= NN * 16) return;
    int row = i >> 4;
    float w = inv[row];
    const float4* src = (const float4*)(x + (size_t)i * 8);
    float4 a = src[0], bq = src[1];
    uint4 o;
    o.x = bf16_rne(a.x * w)  | (bf16_rne(a.y * w) << 16);
    o.y = bf16_rne(a.z * w)  | (bf16_rne(a.w * w) << 16);
    o.z = bf16_rne(bq.x * w) | (bf16_rne(bq.y * w) << 16);
    o.w = bf16_rne(bq.z * w) | (bf16_rne(bq.w * w) << 16);
    ((uint4*)xnb4)[i] = o;
}

// ---------------- gather: out[n] = inv[n]*(xnb[n] + sum_s xnb[s]) ----------------
#define ACC2(u) do { \
    ax += __uint_as_float((u).x << 16); \
    ay += __uint_as_float((u).x & 0xffff0000u); \
    az += __uint_as_float((u).y << 16); \
    aw += __uint_as_float((u).y & 0xffff0000u); } while (0)

__global__ __launch_bounds__(256) void gather_kernel(const unsigned* __restrict__ xnb,
                                                     const float* __restrict__ inv,
                                                     const int* __restrict__ off,
                                                     const int* __restrict__ cnt,
                                                     const unsigned short* __restrict__ csr,
                                                     float* __restrict__ out) {
    int wid = (blockIdx.x * blockDim.x + threadIdx.x) >> 6;
    if (wid >= NN) return;
    int lane = threadIdx.x & 63;
    int half = lane >> 5;
    int col4 = lane & 31;  // owns cols 4*col4 .. 4*col4+3 (one uint2)

    float ax = 0.f, ay = 0.f, az = 0.f, aw = 0.f;
    const uint2* xb = (const uint2*)xnb;  // 32 uint2 per row
    if (half == 0) {
        uint2 u = xb[(size_t)wid * 32 + col4];
        ACC2(u);
    }
    int n = cnt[wid];
    const unsigned short* row = csr + off[wid];
    int i = half;
    for (; i + 14 < n; i += 16) {
        int s0 = row[i],      s1 = row[i + 2],  s2 = row[i + 4],  s3 = row[i + 6];
        int s4 = row[i + 8],  s5 = row[i + 10], s6 = row[i + 12], s7 = row[i + 14];
        uint2 u0 = xb[(size_t)s0 * 32 + col4];
        uint2 u1 = xb[(size_t)s1 * 32 + col4];
        uint2 u2 = xb[(size_t)s2 * 32 + col4];
        uint2 u3 = xb[(size_t)s3 * 32 + col4];
        uint2 u4 = xb[(size_t)s4 * 32 + col4];
        uint2 u5 = xb[(size_t)s5 * 32 + col4];
        uint2 u6 = xb[(size_t)s6 * 32 + col4];
        uint2 u7 = xb[(size_t)s7 * 32 + col4];
        ACC2(u0); ACC2(u1); ACC2(u2); ACC2(u3);
        ACC2(u4); ACC2(u5); ACC2(u6); ACC2(u7);
    }
    for (; i + 6 < n; i += 8) {
        int s0 = row[i], s1 = row[i + 2], s2 = row[i + 4], s3 = row[i + 6];
        uint2 u0 = xb[(size_t)s0 * 32 + col4];
        uint2 u1 = xb[(size_t)s1 * 32 + col4];
        uint2 u2 = xb[(size_t)s2 * 32 + col4];
        uint2 u3 = xb[(size_t)s3 * 32 + col4];
        ACC2(u0); ACC2(u1); ACC2(u2); ACC2(u3);
    }
    for (; i < n; i += 2) {
        int s = row[i];
        uint2 u = xb[(size_t)s * 32 + col4];
        ACC2(u);
    }
    ax += __shfl_xor(ax, 32, 64);
    ay += __shfl_xor(ay, 32, 64);
    az += __shfl_xor(az, 32, 64);
    aw += __shfl_xor(aw, 32, 64);
    if (half == 0) {
        float wn = inv[wid];
        float4 o;
        o.x = ax * wn; o.y = ay * wn; o.z = az * wn; o.w = aw * wn;
        ((float4*)(out + (size_t)wid * D))[col4] = o;
    }
}

// ---------------- out[r][c] = h[r][:] . Wt[:][c] + b[c]  (in-place in io) ----------------
__global__ __launch_bounds__(256) void gemm_kernel(float* io, const float* __restrict__ Wt,
                                                   const float* __restrict__ b) {
    __shared__ float h[RPB][D];
    int r0 = blockIdx.x * RPB;

    const float4* src4 = (const float4*)(io + (size_t)r0 * D);
    for (int t = threadIdx.x; t < RPB * D / 4; t += 256) {
        ((float4*)h)[t] = src4[t];
    }
    __syncthreads();

    int c = threadIdx.x & 127;
    int rh = threadIdx.x >> 7;  // 0 or 1 -> rows rh*20 .. rh*20+19
    float acc[20];
#pragma unroll
    for (int j = 0; j < 20; ++j) acc[j] = 0.0f;

    for (int k0 = 0; k0 < D; k0 += 4) {
        float w0 = Wt[(k0 + 0) * D + c];
        float w1 = Wt[(k0 + 1) * D + c];
        float w2 = Wt[(k0 + 2) * D + c];
        float w3 = Wt[(k0 + 3) * D + c];
#pragma unroll
        for (int j = 0; j < 20; ++j) {
            float4 hv = *(const float4*)&h[rh * 20 + j][k0];  // LDS broadcast, b128
            acc[j] += hv.x * w0 + hv.y * w1 + hv.z * w2 + hv.w * w3;
        }
    }

    float bc = b[c];
#pragma unroll
    for (int j = 0; j < 20; ++j) {
        io[(size_t)(r0 + rh * 20 + j) * D + c] = acc[j] + bc;
    }
}

extern "C" void kernel_launch(void* const* d_in, const int* in_sizes, int n_in,
                              void* d_out, int out_size, void* d_ws, size_t ws_size,
                              hipStream_t stream) {
    const float* x  = (const float*)d_in[0];
    const int*   ei = (const int*)d_in[1];
    const float* W  = (const float*)d_in[2];
    const float* b  = (const float*)d_in[3];
    float* out = (float*)d_out;

    char* ws = (char*)d_ws;
    float*          inv    = (float*)         (ws + WS_INV);
    int*            cnt    = (int*)           (ws + WS_CNT);
    int*            off    = (int*)           (ws + WS_OFF);
    int*            bsum   = (int*)           (ws + WS_BSUM);
    float*          Wt     = (float*)         (ws + WS_WT);
    unsigned*       psrc_p = (unsigned*)      (ws + WS_A);
    unsigned short* csr    = (unsigned short*)(ws + WS_A);  // overlays psrc_p after reduce_scan
    unsigned*       pdst_p = (unsigned*)      (ws + WS_B);
    int*            bases  = (int*)           (ws + WS_C);
    unsigned*       xnb    = (unsigned*)      (ws + WS_B);  // overlays pdst_p+bases after fill

    fused_pre<<<NCS + NCD + 16, 1024, 0, stream>>>(ei, W, psrc_p, pdst_p, Wt);
    reduce_scan<<<NBS, 256, 0, stream>>>(psrc_p, pdst_p, inv, cnt, off, bsum);
    scan_chunks<<<NBS, 256, 0, stream>>>(pdst_p, bases, off, bsum);
    fill_sorted<<<64, 1024, 0, stream>>>(ei, bases, csr);
    scale_kernel<<<(NN * 16 + 255) / 256, 256, 0, stream>>>(x, inv, xnb);
    gather_kernel<<<(NN * 64 + 255) / 256, 256, 0, stream>>>(xnb, inv, off, cnt, csr, out);
    gemm_kernel<<<NN / RPB, 256, 0, stream>>>(out, Wt, b);
}